// Round 1
// baseline (1027.456 us; speedup 1.0000x reference)
//
#include <hip/hip_runtime.h>

// CIN_51539607712: 3-layer cross-interaction network.
// R = BATCH*EMB = 16384 rows. Per layer: X_{l+1}[r,:] = act( (xl[r]⊗x0[r]) @ W + b ),
// W shape (h*32, 128). Output: per-layer sum over d (16 rows/batch), concat -> (1024, 384).

#define R_TOTAL 16384

// Build X0[r][m] = inputs[b][m][d], r = b*16 + d.  (1024,32,16) -> (16384,32)
__global__ __launch_bounds__(256) void build_x0(const float* __restrict__ in,
                                                float* __restrict__ x0) {
    int tid = blockIdx.x * 256 + threadIdx.x;      // 0 .. 524287
    int m = tid & 31;
    int r = tid >> 5;
    int d = r & 15;
    int b = r >> 4;
    x0[tid] = in[b * 512 + m * 16 + d];
}

// Block: 64 rows x 128 cols, 256 threads, each thread 4 rows x 8 cols.
// H = width of xin (32 or 128). K = H*32.
template <int H, bool RELU, bool STORE_X>
__global__ __launch_bounds__(256, 1) void layer_kernel(
    const float* __restrict__ xin,   // R x H   (for H==32 this equals x0)
    const float* __restrict__ x0,    // R x 32
    const float* __restrict__ W,     // (H*32) x 128
    const float* __restrict__ bias,  // 128
    float* __restrict__ xout,        // R x 128 (if STORE_X)
    float* __restrict__ osum)        // d_out + layer_offset; stride 384 per batch
{
    constexpr int XS = (H == 32) ? 36 : 132;       // padded LDS row strides
    __shared__ float x0t[64 * 36];                 // 9216 B *4
    __shared__ float wt[32 * 128];                 // 16 KB, reused as psum[16][128]
    __shared__ float xint[(H == 32) ? 4 : 64 * 132];

    const int tid = threadIdx.x;
    const int r0 = blockIdx.x * 64;
    const int rq = tid >> 4;        // 0..15  -> row quad
    const int co = tid & 15;        // 0..15  -> col octet
    const int rbase = rq * 4;

    // ---- stage x0 tile: 64x32 contiguous floats, write with stride 36 ----
    {
        const float4* s4 = (const float4*)(x0 + r0 * 32);
        float4* d4 = (float4*)x0t;
        #pragma unroll
        for (int i = tid; i < 512; i += 256) {
            int r = i >> 3, c4 = i & 7;
            d4[r * 9 + c4] = s4[i];
        }
    }
    // ---- stage xin tile (only H==128): 64x128 contiguous, stride 132 ----
    if constexpr (H == 128) {
        const float4* s4 = (const float4*)(xin + r0 * 128);
        float4* d4 = (float4*)xint;
        #pragma unroll
        for (int i = tid; i < 2048; i += 256) {
            int r = i >> 5, c4 = i & 31;
            d4[r * 33 + c4] = s4[i];
        }
    }
    const float* xi = (H == 32) ? x0t : xint;

    // ---- register prefetch of W chunk h=0 (32x128 floats = 1024 float4) ----
    const float4* Wg = (const float4*)W;
    float4 wreg[4];
    #pragma unroll
    for (int k = 0; k < 4; ++k) wreg[k] = Wg[tid + k * 256];

    float acc[4][8];
    #pragma unroll
    for (int rr = 0; rr < 4; ++rr)
        #pragma unroll
        for (int j = 0; j < 8; ++j) acc[rr][j] = 0.f;

    for (int h = 0; h < H; ++h) {
        __syncthreads();                            // wt readers of h-1 done
        {
            float4* wt4 = (float4*)wt;
            #pragma unroll
            for (int k = 0; k < 4; ++k) wt4[tid + k * 256] = wreg[k];
        }
        __syncthreads();                            // wt (and tiles on h==0) visible
        if (h + 1 < H) {
            const float4* Wn = Wg + (size_t)(h + 1) * 1024;
            #pragma unroll
            for (int k = 0; k < 4; ++k) wreg[k] = Wn[tid + k * 256];
        }

        float xv[4];
        #pragma unroll
        for (int rr = 0; rr < 4; ++rr) xv[rr] = xi[(rbase + rr) * XS + h];

        #pragma unroll
        for (int m4 = 0; m4 < 8; ++m4) {
            float4 xq[4];
            #pragma unroll
            for (int rr = 0; rr < 4; ++rr)
                xq[rr] = *(const float4*)&x0t[(rbase + rr) * 36 + m4 * 4];
            #pragma unroll
            for (int mm = 0; mm < 4; ++mm) {
                int m = m4 * 4 + mm;
                float4 wa = *(const float4*)&wt[m * 128 + co * 8];
                float4 wb = *(const float4*)&wt[m * 128 + co * 8 + 4];
                #pragma unroll
                for (int rr = 0; rr < 4; ++rr) {
                    float xm = (mm == 0) ? xq[rr].x : (mm == 1) ? xq[rr].y
                             : (mm == 2) ? xq[rr].z : xq[rr].w;
                    float z = xv[rr] * xm;
                    acc[rr][0] += z * wa.x; acc[rr][1] += z * wa.y;
                    acc[rr][2] += z * wa.z; acc[rr][3] += z * wa.w;
                    acc[rr][4] += z * wb.x; acc[rr][5] += z * wb.y;
                    acc[rr][6] += z * wb.z; acc[rr][7] += z * wb.w;
                }
            }
        }
    }

    // ---- epilogue: bias, ReLU, optional store, d-sum ----
    __syncthreads();                // all wt reads done; reuse wt as psum[16][128]
    float* psum = wt;

    float b8[8];
    #pragma unroll
    for (int j = 0; j < 8; ++j) b8[j] = bias[co * 8 + j];

    float prow[8];
    #pragma unroll
    for (int j = 0; j < 8; ++j) prow[j] = 0.f;

    #pragma unroll
    for (int rr = 0; rr < 4; ++rr) {
        int r = r0 + rbase + rr;
        #pragma unroll
        for (int j = 0; j < 8; ++j) {
            float v = acc[rr][j] + b8[j];
            if (RELU) v = fmaxf(v, 0.f);
            acc[rr][j] = v;
            prow[j] += v;
        }
        if constexpr (STORE_X) {
            *(float4*)&xout[(size_t)r * 128 + co * 8] =
                make_float4(acc[rr][0], acc[rr][1], acc[rr][2], acc[rr][3]);
            *(float4*)&xout[(size_t)r * 128 + co * 8 + 4] =
                make_float4(acc[rr][4], acc[rr][5], acc[rr][6], acc[rr][7]);
        }
    }
    #pragma unroll
    for (int j = 0; j < 8; ++j) psum[rq * 128 + co * 8 + j] = prow[j];
    __syncthreads();

    // 4 batch elements x 128 cols = 512 outputs; each sums 4 psum rows.
    for (int i = tid; i < 512; i += 256) {
        int bl = i >> 7, col = i & 127;
        float s = psum[(bl * 4 + 0) * 128 + col] + psum[(bl * 4 + 1) * 128 + col] +
                  psum[(bl * 4 + 2) * 128 + col] + psum[(bl * 4 + 3) * 128 + col];
        int b = (r0 >> 4) + bl;
        osum[(size_t)b * 384 + col] = s;
    }
}

extern "C" void kernel_launch(void* const* d_in, const int* in_sizes, int n_in,
                              void* d_out, int out_size, void* d_ws, size_t ws_size,
                              hipStream_t stream) {
    const float* in = (const float*)d_in[0];
    const float* W0 = (const float*)d_in[1];
    const float* b0 = (const float*)d_in[2];
    const float* W1 = (const float*)d_in[3];
    const float* b1 = (const float*)d_in[4];
    const float* W2 = (const float*)d_in[5];
    const float* b2 = (const float*)d_in[6];
    float* out = (float*)d_out;

    float* X0 = (float*)d_ws;                       // 16384*32
    float* X1 = X0 + (size_t)R_TOTAL * 32;          // 16384*128
    float* X2 = X1 + (size_t)R_TOTAL * 128;         // 16384*128
    // ws usage: (32+128+128)*16384*4 = 18 MB

    build_x0<<<R_TOTAL * 32 / 256, 256, 0, stream>>>(in, X0);
    layer_kernel<32,  true,  true ><<<R_TOTAL / 64, 256, 0, stream>>>(X0, X0, W0, b0, X1, out + 0);
    layer_kernel<128, true,  true ><<<R_TOTAL / 64, 256, 0, stream>>>(X1, X0, W1, b1, X2, out + 128);
    layer_kernel<128, false, false><<<R_TOTAL / 64, 256, 0, stream>>>(X2, X0, W2, b2, nullptr, out + 256);
}

// Round 2
// 216.246 us; speedup vs baseline: 4.7513x; 4.7513x over previous
//
#include <hip/hip_runtime.h>

// CIN_51539607712 — bf16x3 split-precision MFMA version.
// out[r,n] = act( sum_k z[r,k] W[k,n] + b[n] ),  z[r, h*32+m] = xl[r,h]*x0[r,m]
// GEMM shapes: M=16384, N=128, K in {1024,4096,4096}. Each value split v=hi+lo
// (bf16 each); 3 MFMAs per product term (ah*bh + ah*bl + al*bh), fp32 acc.
//
// Block = 64 rows, 256 thr = 4 waves: wave w -> (kh=w&1 K-half, nh=w>>1 N-half).
// Wave owns 64 rows x 64 cols x K/2: acc 4x4 frags of 16x16x32 MFMA.
// W pre-split+pre-swizzled in ws as 8KB tile-halves ([64 n][8 blocks of 16B],
// block (h*4+q) stored at position (h*4+q)^(n&7) -> conflict-free b128 reads,
// global_load_lds-stageable with zero padding). Per-wave double buffer, no
// K-loop barriers (per-wave vmcnt(0) only). LDS = 64 KB exactly.

typedef unsigned int u32;
typedef __attribute__((ext_vector_type(8))) short short8;
typedef __attribute__((ext_vector_type(4))) float f32x4;
typedef __attribute__((ext_vector_type(4))) u32 u32x4;

#define R_TOTAL 16384
#define GLOBAL_AS __attribute__((address_space(1)))
#define LDS_AS __attribute__((address_space(3)))

union PackU { u32 u[4]; short8 s; };
union PackB { u32x4 v; short8 s; };

// pack bf16(a) into low half, bf16(b) into high half (truncation)
__device__ __forceinline__ u32 pack_trunc(float a, float b) {
  return __builtin_amdgcn_perm(__float_as_uint(b), __float_as_uint(a), 0x07060302u);
}

// ---------------- prep: X0[r][m] = in[b][m][d], r = b*16+d ----------------
__global__ __launch_bounds__(256) void build_x0(const float* __restrict__ in,
                                                float* __restrict__ x0) {
  __shared__ float t[4096];
  const int tid = threadIdx.x;
  const int b0 = blockIdx.x * 8;
  #pragma unroll
  for (int rep = 0; rep < 4; ++rep) {
    int idx = tid + rep * 256;
    *(float4*)&t[idx * 4] = *(const float4*)&in[(size_t)b0 * 512 + idx * 4];
  }
  __syncthreads();
  #pragma unroll
  for (int rep = 0; rep < 4; ++rep) {
    int idx = tid + rep * 256;
    int bl = idx >> 7, rem = idx & 127;
    int d = rem >> 3, m4 = (rem & 7) * 4;
    float4 v;
    v.x = t[bl * 512 + (m4 + 0) * 16 + d];
    v.y = t[bl * 512 + (m4 + 1) * 16 + d];
    v.z = t[bl * 512 + (m4 + 2) * 16 + d];
    v.w = t[bl * 512 + (m4 + 3) * 16 + d];
    *(float4*)&x0[(size_t)(b0 + bl) * 512 + d * 32 + m4] = v;
  }
}

// ---------------- prep: split+swizzle W into tile-half images ----------------
// grid = NT*2 blocks; block handles (tile t = bid>>1, nhalf = bid&1).
// Output image (8192 B): [nl 0..63][p 0..7] 16B blocks; content of position p is
// logical block l = p ^ (nl&7); l = h*4+q -> part h (0=hi,1=lo) of W[t*32+q*8+j][n].
__global__ __launch_bounds__(256) void swizzle_w(const float* __restrict__ W,
                                                 u32* __restrict__ wt) {
  __shared__ float wl[32 * 68];
  const int tid = threadIdx.x;
  const int t = blockIdx.x >> 1, nh = blockIdx.x & 1;
  #pragma unroll
  for (int rep = 0; rep < 2; ++rep) {
    int idx = tid + rep * 256;          // 512 float4 = 32 k x 16 f4
    int kk = idx >> 4, c4 = idx & 15;
    float4 v = *(const float4*)&W[(size_t)(t * 32 + kk) * 128 + nh * 64 + c4 * 4];
    wl[kk * 68 + c4 * 4 + 0] = v.x;
    wl[kk * 68 + c4 * 4 + 1] = v.y;
    wl[kk * 68 + c4 * 4 + 2] = v.z;
    wl[kk * 68 + c4 * 4 + 3] = v.w;
  }
  __syncthreads();
  #pragma unroll
  for (int rep = 0; rep < 2; ++rep) {
    int b = tid + rep * 256;            // 512 out blocks
    int nl = b >> 3, p = b & 7;
    int l = p ^ (nl & 7);
    int h = l >> 2, q = l & 3;
    u32 out[4];
    #pragma unroll
    for (int jj = 0; jj < 4; ++jj) {
      float v0 = wl[(q * 8 + 2 * jj + 0) * 68 + nl];
      float v1 = wl[(q * 8 + 2 * jj + 1) * 68 + nl];
      if (h == 0) {
        out[jj] = pack_trunc(v0, v1);
      } else {
        float l0 = v0 - __uint_as_float(__float_as_uint(v0) & 0xffff0000u);
        float l1 = v1 - __uint_as_float(__float_as_uint(v1) & 0xffff0000u);
        out[jj] = pack_trunc(l0, l1);
      }
    }
    u32* dst = wt + (size_t)(t * 2 + nh) * 2048 + nl * 32 + p * 4;
    *(u32x4*)dst = u32x4{out[0], out[1], out[2], out[3]};
  }
}

// ---------------- per-wave tile staging: 8192 B via global_load_lds ----------
__device__ __forceinline__ void stage8k(const u32* g, u32* l, int lane) {
  const GLOBAL_AS u32* gp = (const GLOBAL_AS u32*)g;
  LDS_AS u32* lp = (LDS_AS u32*)l;
  #pragma unroll
  for (int i = 0; i < 8; ++i)
    __builtin_amdgcn_global_load_lds(gp + i * 256 + lane * 4, lp + i * 256, 16, 0, 0);
}

// ---------------- main layer kernel ----------------
template <int NT, bool RELU, bool STORE_X>
__global__ __launch_bounds__(256, 1) void layer_mfma(
    const float* __restrict__ xin,   // R x NT
    const float* __restrict__ x0,    // R x 32
    const u32* __restrict__ wt,      // NT*2 tile-half images
    const float* __restrict__ bias,  // 128
    float* __restrict__ xout,        // R x 128 (if STORE_X)
    float* __restrict__ osum)        // d_out + layer offset, stride 384
{
  constexpr int HT = NT / 2;
  __shared__ u32 smem[16384];  // 64 KB exactly

  const int tid = threadIdx.x;
  const int w = tid >> 6, lane = tid & 63;
  const int ln15 = lane & 15, q = lane >> 4;
  const int kh = w & 1, nh = w >> 1;
  const int r0 = blockIdx.x * 64;
  const int sw = ln15 & 7;  // swizzle key
  u32* mybuf = smem + w * 4096;

  // x0 fragment values in registers (whole kernel): rows f*16+ln15, m = q*8+j
  float x0v[4][8];
  #pragma unroll
  for (int f = 0; f < 4; ++f) {
    const float4* p = (const float4*)&x0[(size_t)(r0 + f * 16 + ln15) * 32 + q * 8];
    float4 a = p[0], b = p[1];
    x0v[f][0] = a.x; x0v[f][1] = a.y; x0v[f][2] = a.z; x0v[f][3] = a.w;
    x0v[f][4] = b.x; x0v[f][5] = b.y; x0v[f][6] = b.z; x0v[f][7] = b.w;
  }

  f32x4 acc[4][4];
  #pragma unroll
  for (int f = 0; f < 4; ++f)
    #pragma unroll
    for (int c = 0; c < 4; ++c) acc[f][c] = f32x4{0.f, 0.f, 0.f, 0.f};

  const int t0 = kh * HT;
  stage8k(wt + (size_t)(t0 * 2 + nh) * 2048, mybuf, lane);
  float xv[4];
  #pragma unroll
  for (int f = 0; f < 4; ++f)
    xv[f] = xin[(size_t)(r0 + f * 16 + ln15) * NT + t0];

  for (int i = 0; i < HT; ++i) {
    const int cur = i & 1;
    __builtin_amdgcn_s_waitcnt(0x0F70);  // vmcnt(0): tile + xv prefetch ready

    // build split A fragments: z = xv * x0v; hi = trunc-bf16, lo = residual
    PackU Ah[4], Al[4];
    #pragma unroll
    for (int f = 0; f < 4; ++f) {
      #pragma unroll
      for (int jj = 0; jj < 4; ++jj) {
        float z0 = xv[f] * x0v[f][2 * jj + 0];
        float z1 = xv[f] * x0v[f][2 * jj + 1];
        Ah[f].u[jj] = pack_trunc(z0, z1);
        float h0 = __uint_as_float(__float_as_uint(z0) & 0xffff0000u);
        float h1 = __uint_as_float(__float_as_uint(z1) & 0xffff0000u);
        Al[f].u[jj] = pack_trunc(z0 - h0, z1 - h1);
      }
    }

    // prefetch next xl column + stage next W tile-half (overlaps MFMA below)
    const int tn = t0 + ((i + 1 < HT) ? (i + 1) : i);
    float xvn[4];
    #pragma unroll
    for (int f = 0; f < 4; ++f)
      xvn[f] = xin[(size_t)(r0 + f * 16 + ln15) * NT + tn];
    if (i + 1 < HT)
      stage8k(wt + (size_t)(tn * 2 + nh) * 2048, mybuf + (1 - cur) * 2048, lane);

    const u32* buf = mybuf + cur * 2048;
    #pragma unroll
    for (int c = 0; c < 4; ++c) {
      const int nl = c * 16 + ln15;
      const u32* row = buf + nl * 32;
      PackB bh, bl;
      bh.v = *(const u32x4*)(row + ((q ^ sw) * 4));
      bl.v = *(const u32x4*)(row + (((4 + q) ^ sw) * 4));
      #pragma unroll
      for (int f = 0; f < 4; ++f) {
        acc[f][c] = __builtin_amdgcn_mfma_f32_16x16x32_bf16(Ah[f].s, bh.s, acc[f][c], 0, 0, 0);
        acc[f][c] = __builtin_amdgcn_mfma_f32_16x16x32_bf16(Ah[f].s, bl.s, acc[f][c], 0, 0, 0);
        acc[f][c] = __builtin_amdgcn_mfma_f32_16x16x32_bf16(Al[f].s, bh.s, acc[f][c], 0, 0, 0);
      }
    }
    #pragma unroll
    for (int f = 0; f < 4; ++f) xv[f] = xvn[f];
  }

  // ---------------- epilogue: kh-pair reduction + bias/relu/store/d-sum ------
  __syncthreads();  // all waves done with K-loop (LDS about to be reused)
  if (kh == 1) {
    u32* reg = smem + nh * 4096;  // [f][c][lane][reg] b128 per lane
    #pragma unroll
    for (int f = 0; f < 4; ++f)
      #pragma unroll
      for (int c = 0; c < 4; ++c)
        *(f32x4*)(reg + ((size_t)(f * 4 + c) * 64 + lane) * 4) = acc[f][c];
  }
  __syncthreads();
  if (kh == 0) {
    const u32* reg = smem + nh * 4096;
    float bs[4];
    #pragma unroll
    for (int c = 0; c < 4; ++c) bs[c] = bias[nh * 64 + c * 16 + ln15];
    #pragma unroll
    for (int f = 0; f < 4; ++f) {
      #pragma unroll
      for (int c = 0; c < 4; ++c) {
        f32x4 part = *(const f32x4*)(reg + ((size_t)(f * 4 + c) * 64 + lane) * 4);
        f32x4 v = acc[f][c] + part + bs[c];
        if (RELU) {
          v.x = fmaxf(v.x, 0.f); v.y = fmaxf(v.y, 0.f);
          v.z = fmaxf(v.z, 0.f); v.w = fmaxf(v.w, 0.f);
        }
        const int col = nh * 64 + c * 16 + ln15;
        if (STORE_X) {
          #pragma unroll
          for (int rr = 0; rr < 4; ++rr)
            xout[(size_t)(r0 + f * 16 + q * 4 + rr) * 128 + col] = v[rr];
        }
        float s = v.x + v.y + v.z + v.w;           // partial d-sum (4 rows)
        s += __shfl_xor(s, 16, 64);                // reduce across quads
        s += __shfl_xor(s, 32, 64);
        if (q == 0)
          osum[(size_t)((r0 >> 4) + f) * 384 + col] = s;
      }
    }
  }
}

extern "C" void kernel_launch(void* const* d_in, const int* in_sizes, int n_in,
                              void* d_out, int out_size, void* d_ws, size_t ws_size,
                              hipStream_t stream) {
  const float* in = (const float*)d_in[0];
  const float* W0 = (const float*)d_in[1];
  const float* b0 = (const float*)d_in[2];
  const float* W1 = (const float*)d_in[3];
  const float* b1 = (const float*)d_in[4];
  const float* W2 = (const float*)d_in[5];
  const float* b2 = (const float*)d_in[6];
  float* out = (float*)d_out;

  float* X0 = (float*)d_ws;                          // 16384*32 f32   (2 MB)
  float* X1 = X0 + (size_t)R_TOTAL * 32;             // 16384*128 f32  (8 MB)
  float* X2 = X1 + (size_t)R_TOTAL * 128;            // 16384*128 f32  (8 MB)
  u32* Wt0 = (u32*)(X2 + (size_t)R_TOTAL * 128);     // 32*2*2048 u32  (0.5 MB)
  u32* Wt1 = Wt0 + (size_t)32 * 2 * 2048;            // 128*2*2048 u32 (2 MB)
  u32* Wt2 = Wt1 + (size_t)128 * 2 * 2048;           // 128*2*2048 u32 (2 MB)
  // total ws: ~22.5 MB

  build_x0<<<128, 256, 0, stream>>>(in, X0);
  swizzle_w<<<64, 256, 0, stream>>>(W0, Wt0);
  swizzle_w<<<256, 256, 0, stream>>>(W1, Wt1);
  swizzle_w<<<256, 256, 0, stream>>>(W2, Wt2);

  layer_mfma<32, true, true><<<256, 256, 0, stream>>>(X0, X0, Wt0, b0, X1, out + 0);
  layer_mfma<128, true, true><<<256, 256, 0, stream>>>(X1, X0, Wt1, b1, X2, out + 128);
  layer_mfma<128, false, false><<<256, 256, 0, stream>>>(X2, X0, Wt2, b2, nullptr, out + 256);
}

// Round 3
// 185.653 us; speedup vs baseline: 5.5343x; 1.1648x over previous
//
#include <hip/hip_runtime.h>

// CIN_51539607712 — R3: factorized MFMA (loop-invariant A = x0-splits).
// out[r,n] = sum_h xl[r,h] * Y_h[r,n],  Y_h[r,n] = sum_m x0[r,m] W[h*32+m,n].
// Y via 3 bf16 MFMAs (x0h*wh + x0h*wl + x0l*wh), then fp32 fma by xl (exact).
// Block = 64 rows x 128 cols, 512 thr = 8 waves: (kh = w&1 K-half, nq = w>>1
// N-quarter). Per-wave private 4 KB W quarter-images, double-buffered, XOR-
// swizzled, staged via global_load_lds w=16; barrier-free K-loop (per-wave
// vmcnt(0) only). LDS = 64 KB. Activations stored TRANSPOSED (XT[t][r]) so the
// per-row xl scalars load as one float4 per frag-row; epilogue transposes
// through wave-private LDS for contiguous 64B stores.

typedef unsigned int u32;
typedef __attribute__((ext_vector_type(8))) short short8;
typedef __attribute__((ext_vector_type(4))) float f32x4;
typedef __attribute__((ext_vector_type(4))) u32 u32x4;

#define R_TOTAL 16384
#define GLOBAL_AS __attribute__((address_space(1)))
#define LDS_AS __attribute__((address_space(3)))

union PackU { u32 u[4]; short8 s; };
union PackB { u32x4 v; short8 s; };

// pack bf16(a) into low half, bf16(b) into high half (truncation)
__device__ __forceinline__ u32 pack_trunc(float a, float b) {
  return __builtin_amdgcn_perm(__float_as_uint(b), __float_as_uint(a), 0x07060302u);
}

// ---------------- prep: X0T[m][b*16+d] = in[b][m][d]  (32 x 16384) ----------
__global__ __launch_bounds__(256) void build_x0t(const float* __restrict__ in,
                                                 float* __restrict__ x0t) {
  __shared__ float t[4096];
  const int tid = threadIdx.x;
  const int b0 = blockIdx.x * 8;
  #pragma unroll
  for (int rep = 0; rep < 4; ++rep) {
    int idx = tid + rep * 256;
    *(float4*)&t[idx * 4] = *(const float4*)&in[(size_t)b0 * 512 + idx * 4];
  }
  __syncthreads();
  #pragma unroll
  for (int rep = 0; rep < 4; ++rep) {
    int idx = tid + rep * 256;     // 0..1023: m(32) x bl(8) x dq(4)
    int m = idx >> 5, rem = idx & 31;
    int bl = rem >> 2, dq = rem & 3;
    *(float4*)&x0t[(size_t)m * R_TOTAL + (b0 + bl) * 16 + dq * 4] =
        *(const float4*)&t[bl * 512 + m * 16 + dq * 4];
  }
}

// ---------------- prep: split+swizzle W into 4 KB quarter images -------------
// Block (t = bid>>2, nq = bid&3). Image: [nl 0..31][p 0..7] 16B blocks; position
// p holds logical block l = p ^ (nl&7); l = h*4+q -> split-part h of
// W[t*32+q*8+j][nq*32+nl], j pairs packed (even=lo half, odd=hi half).
__global__ __launch_bounds__(256) void swizzle_w(const float* __restrict__ W,
                                                 u32* __restrict__ wt) {
  __shared__ float wl[32 * 33];
  const int tid = threadIdx.x;
  const int t = blockIdx.x >> 2, nq = blockIdx.x & 3;
  {
    int kk = tid >> 3, c4 = tid & 7;
    float4 v = *(const float4*)&W[(size_t)(t * 32 + kk) * 128 + nq * 32 + c4 * 4];
    wl[kk * 33 + c4 * 4 + 0] = v.x;
    wl[kk * 33 + c4 * 4 + 1] = v.y;
    wl[kk * 33 + c4 * 4 + 2] = v.z;
    wl[kk * 33 + c4 * 4 + 3] = v.w;
  }
  __syncthreads();
  {
    int nl = tid >> 3, p = tid & 7;
    int l = p ^ (nl & 7);
    int h = l >> 2, q = l & 3;
    u32 o[4];
    #pragma unroll
    for (int jj = 0; jj < 4; ++jj) {
      float v0 = wl[(q * 8 + 2 * jj + 0) * 33 + nl];
      float v1 = wl[(q * 8 + 2 * jj + 1) * 33 + nl];
      if (h == 1) {
        v0 -= __uint_as_float(__float_as_uint(v0) & 0xffff0000u);
        v1 -= __uint_as_float(__float_as_uint(v1) & 0xffff0000u);
      }
      o[jj] = pack_trunc(v0, v1);
    }
    *(u32x4*)(wt + (size_t)(t * 4 + nq) * 1024 + nl * 32 + p * 4) =
        u32x4{o[0], o[1], o[2], o[3]};
  }
}

// ---------------- per-wave tile staging: 4096 B via global_load_lds ----------
__device__ __forceinline__ void stage4k(const u32* g, u32* l, int lane) {
  const GLOBAL_AS u32* gp = (const GLOBAL_AS u32*)g;
  LDS_AS u32* lp = (LDS_AS u32*)l;
  #pragma unroll
  for (int i = 0; i < 4; ++i)
    __builtin_amdgcn_global_load_lds(gp + i * 256 + lane * 4, lp + i * 256, 16, 0, 0);
}

// ---------------- main layer kernel ----------------
template <int NT, bool RELU, bool STORE_X>
__global__ __launch_bounds__(512, 2) void layer_mfma(
    const float* __restrict__ xt,    // NT x R (transposed prev activation)
    const float* __restrict__ x0t,   // 32 x R
    const u32* __restrict__ wt,      // NT*4 quarter images (1024 u32 each)
    const float* __restrict__ bias,  // 128
    float* __restrict__ xoutT,       // 128 x R (if STORE_X)
    float* __restrict__ osum)        // d_out + layer offset, stride 384
{
  constexpr int HT = NT / 2;
  __shared__ u32 smem[16384];        // 64 KB: 8 waves x 2 KB-u32 (4 KB dbuf x2)

  const int tid = threadIdx.x;
  const int w = tid >> 6, lane = tid & 63;
  const int ln15 = lane & 15, q = lane >> 4;
  const int kh = w & 1, nq = w >> 1;
  const int r0 = blockIdx.x * 64;
  const int sw = ln15 & 7;
  u32* mybuf = smem + w * 2048;

  // ---- loop-invariant A fragments: split x0 rows (A[i=ln15][k=q*8+j]) ----
  PackU Ah[4], Al[4];
  #pragma unroll
  for (int f = 0; f < 4; ++f) {
    const int rbase = r0 + f * 16 + ln15;
    float e[8];
    #pragma unroll
    for (int j = 0; j < 8; ++j) e[j] = x0t[(size_t)(q * 8 + j) * R_TOTAL + rbase];
    #pragma unroll
    for (int jj = 0; jj < 4; ++jj) {
      float z0 = e[2 * jj], z1 = e[2 * jj + 1];
      Ah[f].u[jj] = pack_trunc(z0, z1);
      float h0 = __uint_as_float(__float_as_uint(z0) & 0xffff0000u);
      float h1 = __uint_as_float(__float_as_uint(z1) & 0xffff0000u);
      Al[f].u[jj] = pack_trunc(z0 - h0, z1 - h1);
    }
  }

  f32x4 acc[4][2];
  #pragma unroll
  for (int f = 0; f < 4; ++f)
    #pragma unroll
    for (int c = 0; c < 2; ++c) acc[f][c] = f32x4{0.f, 0.f, 0.f, 0.f};
  const f32x4 zero4 = {0.f, 0.f, 0.f, 0.f};

  const int t0 = kh * HT;
  stage4k(wt + (size_t)(t0 * 4 + nq) * 1024, mybuf, lane);
  const float* xlp = xt + (size_t)t0 * R_TOTAL + r0;
  f32x4 xln[4];
  #pragma unroll
  for (int f = 0; f < 4; ++f) xln[f] = *(const f32x4*)(xlp + f * 16 + q * 4);

  #pragma unroll 2
  for (int i = 0; i < HT; ++i) {
    __builtin_amdgcn_s_waitcnt(0x0F70);  // vmcnt(0): tile i + xl(i) ready

    f32x4 xlc[4];
    #pragma unroll
    for (int f = 0; f < 4; ++f) xlc[f] = xln[f];

    if (i + 1 < HT) {
      stage4k(wt + (size_t)((t0 + i + 1) * 4 + nq) * 1024,
              mybuf + ((i + 1) & 1) * 1024, lane);
      xlp += R_TOTAL;
      #pragma unroll
      for (int f = 0; f < 4; ++f) xln[f] = *(const f32x4*)(xlp + f * 16 + q * 4);
    }

    const u32* buf = mybuf + (i & 1) * 1024;
    #pragma unroll
    for (int c = 0; c < 2; ++c) {
      const u32* row = buf + (c * 16 + ln15) * 32;
      PackB bh, bl;
      bh.v = *(const u32x4*)(row + ((q ^ sw) * 4));
      bl.v = *(const u32x4*)(row + (((4 + q) ^ sw) * 4));
      #pragma unroll
      for (int f = 0; f < 4; ++f) {
        f32x4 Y = __builtin_amdgcn_mfma_f32_16x16x32_bf16(Ah[f].s, bh.s, zero4, 0, 0, 0);
        Y = __builtin_amdgcn_mfma_f32_16x16x32_bf16(Ah[f].s, bl.s, Y, 0, 0, 0);
        Y = __builtin_amdgcn_mfma_f32_16x16x32_bf16(Al[f].s, bh.s, Y, 0, 0, 0);
        acc[f][c] += xlc[f] * Y;   // fp32 fma, xl untruncated
      }
    }
  }

  // ---------------- epilogue ----------------
  __syncthreads();                  // K-loop LDS regions now reusable
  if (kh == 1) {                    // dump partial acc into own region (8 KB)
    u32* reg = mybuf;
    #pragma unroll
    for (int f = 0; f < 4; ++f)
      #pragma unroll
      for (int c = 0; c < 2; ++c)
        *(f32x4*)(reg + ((size_t)(f * 2 + c) * 64 + lane) * 4) = acc[f][c];
  }
  __syncthreads();
  if (kh == 0) {
    const u32* reg = smem + (w + 1) * 2048;   // partner (kh=1, same nq)
    float bs[2];
    #pragma unroll
    for (int c = 0; c < 2; ++c) bs[c] = bias[nq * 32 + c * 16 + ln15];

    f32x4 vv[4][2];
    #pragma unroll
    for (int f = 0; f < 4; ++f) {
      #pragma unroll
      for (int c = 0; c < 2; ++c) {
        f32x4 part = *(const f32x4*)(reg + ((size_t)(f * 2 + c) * 64 + lane) * 4);
        f32x4 v = acc[f][c] + part;
        v.x += bs[c]; v.y += bs[c]; v.z += bs[c]; v.w += bs[c];
        if (RELU) {
          v.x = fmaxf(v.x, 0.f); v.y = fmaxf(v.y, 0.f);
          v.z = fmaxf(v.z, 0.f); v.w = fmaxf(v.w, 0.f);
        }
        vv[f][c] = v;
        float s = v.x + v.y + v.z + v.w;       // 4 rows of batch (r0>>4)+f
        s += __shfl_xor(s, 16, 64);
        s += __shfl_xor(s, 32, 64);
        if (q == 0)
          osum[(size_t)((r0 >> 4) + f) * 384 + nq * 32 + c * 16 + ln15] = s;
      }
    }

    if (STORE_X) {
      // transpose via own LDS region, then 64B-contiguous stores to XT.
      u32* myreg = mybuf;
      #pragma unroll
      for (int f = 0; f < 4; ++f)
        #pragma unroll
        for (int c = 0; c < 2; ++c)
          *(f32x4*)(myreg + ((size_t)(f * 2 + c) * 64 + lane) * 4) = vv[f][c];
      // element (r_local, lcol): frag (f=r>>4, c=lcol>>4), lane q=(r>>2)&3,
      // ln15=lcol&15, comp rr=r&3. Round (c,s): lane -> col=c*16+(lane>>2),
      // r_local = s*16 + (lane&3)*4.
      #pragma unroll
      for (int c = 0; c < 2; ++c) {
        #pragma unroll
        for (int s = 0; s < 4; ++s) {
          f32x4 vr = *(const f32x4*)(myreg +
              ((size_t)(s * 2 + c) * 64 + (lane & 3) * 16 + (lane >> 2)) * 4);
          const int col = nq * 32 + c * 16 + (lane >> 2);
          *(f32x4*)&xoutT[(size_t)col * R_TOTAL + r0 + s * 16 + (lane & 3) * 4] = vr;
        }
      }
    }
  }
}

extern "C" void kernel_launch(void* const* d_in, const int* in_sizes, int n_in,
                              void* d_out, int out_size, void* d_ws, size_t ws_size,
                              hipStream_t stream) {
  const float* in = (const float*)d_in[0];
  const float* W0 = (const float*)d_in[1];
  const float* b0 = (const float*)d_in[2];
  const float* W1 = (const float*)d_in[3];
  const float* b1 = (const float*)d_in[4];
  const float* W2 = (const float*)d_in[5];
  const float* b2 = (const float*)d_in[6];
  float* out = (float*)d_out;

  float* X0T = (float*)d_ws;                         // 32 x 16384   (2 MB)
  float* X1T = X0T + (size_t)32 * R_TOTAL;           // 128 x 16384  (8 MB)
  float* X2T = X1T + (size_t)128 * R_TOTAL;          // 128 x 16384  (8 MB)
  u32* Wt0 = (u32*)(X2T + (size_t)128 * R_TOTAL);    // 32*4*1024 u32  (0.5 MB)
  u32* Wt1 = Wt0 + (size_t)32 * 4 * 1024;            // 128*4*1024 u32 (2 MB)
  u32* Wt2 = Wt1 + (size_t)128 * 4 * 1024;           // 128*4*1024 u32 (2 MB)
  // total ws: 22.5 MB

  build_x0t<<<128, 256, 0, stream>>>(in, X0T);
  swizzle_w<<<128, 256, 0, stream>>>(W0, Wt0);
  swizzle_w<<<512, 256, 0, stream>>>(W1, Wt1);
  swizzle_w<<<512, 256, 0, stream>>>(W2, Wt2);

  layer_mfma<32, true, true><<<256, 512, 0, stream>>>(X0T, X0T, Wt0, b0, X1T, out + 0);
  layer_mfma<128, true, true><<<256, 512, 0, stream>>>(X1T, X0T, Wt1, b1, X2T, out + 128);
  layer_mfma<128, false, false><<<256, 512, 0, stream>>>(X2T, X0T, Wt2, b2, nullptr, out + 256);
}